// Round 13
// baseline (426.479 us; speedup 1.0000x reference)
//
#include <hip/hip_runtime.h>

#define GN 4096
#define GF 128
#define GB 4

typedef __attribute__((ext_vector_type(8))) short short8;
typedef __attribute__((ext_vector_type(4))) float floatx4;

static __device__ __forceinline__ unsigned short f2bf(float x){
  unsigned int u = __float_as_uint(x);
  u += 0x7FFFu + ((u >> 16) & 1u);            // RNE
  return (unsigned short)(u >> 16);
}

// ---------- Kernel 1: Wh = h@W (f32), si, bf16 E/F tables, bf16 Wh fragment-major ----------
// whB layout: [b][jblk=j>>5][o][j&31] so a wave's B-fragment load is 1KB contiguous.
__global__ __launch_bounds__(256)
void gat_prep(const float* __restrict__ h, const float* __restrict__ W,
              const float* __restrict__ a, unsigned short* __restrict__ whB,
              float* __restrict__ si_g, unsigned short* __restrict__ EFh)
{
  __shared__ float hl[16*GF];                  // 8 KB
  __shared__ float red[2][2][16];
  const int tid = threadIdx.x;
  const int b   = blockIdx.x >> 8;
  const int r0  = (blockIdx.x & 255) << 4;
  const int o = tid & 127, g = tid >> 7;

  const float4* hb4 = (const float4*)(h + ((size_t)(b*GN + r0))*GF);
  ((float4*)hl)[tid]       = hb4[tid];
  ((float4*)hl)[tid + 256] = hb4[tid + 256];
  __syncthreads();

  float acc[8];
  #pragma unroll
  for (int r=0;r<8;++r) acc[r] = 0.f;
  const float* Wp = W + o;
  for (int f4=0; f4<32; ++f4){
    const float w0 = Wp[(f4*4+0)*GF];
    const float w1 = Wp[(f4*4+1)*GF];
    const float w2 = Wp[(f4*4+2)*GF];
    const float w3 = Wp[(f4*4+3)*GF];
    #pragma unroll
    for (int r=0;r<8;++r){
      const float4 h4 = *(const float4*)&hl[((g<<3)+r)*GF + (f4<<2)];
      acc[r] = fmaf(h4.x, w0, acc[r]);
      acc[r] = fmaf(h4.y, w1, acc[r]);
      acc[r] = fmaf(h4.z, w2, acc[r]);
      acc[r] = fmaf(h4.w, w3, acc[r]);
    }
  }

  const float ai = a[o], aj = a[GF + o];
  const int lane = tid & 63, wh = (tid >> 6) & 1;
  #pragma unroll
  for (int r=0;r<8;++r){
    float vi = acc[r]*ai, vj = acc[r]*aj;
    #pragma unroll
    for (int off=32; off; off>>=1){ vi += __shfl_down(vi, off); vj += __shfl_down(vj, off); }
    if (lane == 0){ red[0][wh][(g<<3)+r] = vi; red[1][wh][(g<<3)+r] = vj; }
  }

  // fragment-major bf16 store
  unsigned short us[8] __attribute__((aligned(16)));
  #pragma unroll
  for (int r=0;r<8;++r) us[r] = f2bf(acc[r]);
  {
    const int j0 = r0 + (g<<3);
    unsigned short* dst = whB + (((size_t)(b*128 + (j0>>5))*128 + o)<<5) + (j0&31);
    *(uint4*)dst = *(const uint4*)us;
  }

  __syncthreads();
  if (tid < 16){
    si_g[b*GN + r0 + tid] = red[0][0][tid] + red[0][1][tid];
  } else if (tid < 32){
    const int r = tid - 16;
    const float vsj = red[1][0][r] + red[1][1][r];
    EFh[(size_t)b*8192 + r0 + r]        = f2bf(__expf(vsj));
    EFh[(size_t)b*8192 + 4096 + r0 + r] = f2bf(__expf(0.2f*vsj));
  }
}

// ---------- Kernel 2: fused adj-pack + attention + PV; 64 i-rows/block, 512 threads ----------
// 8 waves, each owns a 512-j slice and FOUR A-fragment rows (m, m+16, m+32, m+48)
// sharing one B octet -> B traffic 256MB device-wide, ~360 VALU cy per B load.
__global__ __launch_bounds__(512, 2)
void gat_main(const int* __restrict__ adj, const unsigned short* __restrict__ whB,
              const float* __restrict__ si_g, const unsigned short* __restrict__ EFh,
              float* __restrict__ out)
{
  __shared__ __align__(16) char smem[16384 + 64*67*8];              // 50.7 KB union
  unsigned short* sEj = (unsigned short*)smem;                      // [0,4096):E [4096,8192):F
  unsigned int*   bitsW  = (unsigned int*)(smem + 16384);           // [64][134]
  unsigned long long* bits64 = (unsigned long long*)(smem + 16384); // [64][67]
  float* smemc = (float*)smem;                                      // combine (after K-loop)

  const int tid  = threadIdx.x;
  const int wave = tid >> 6, lane = tid & 63;
  const int b  = (blockIdx.x >> 1) & 3;                             // XCD-pair per batch
  const int i0 = ((((blockIdx.x >> 3) << 1) | (blockIdx.x & 1))) << 6;
  const int m = lane & 15, quad = lane >> 4, q8 = quad << 3;

  const int jw = wave << 9, jw32 = wave << 4;                       // 512-j slice, 16 jblks

  // --- EF staging (16KB) ---
  {
    const uint4* Eg = (const uint4*)(EFh + (size_t)b*8192);
    uint4* sE4 = (uint4*)sEj;
    sE4[tid]       = Eg[tid];
    sE4[tid + 512] = Eg[tid + 512];
  }

  // --- Phase 1: pack this block's adj tile (64 rows x this wave's 512 j) ---
  // wave w emits 8 u64 words per row at word offset w*8 (stride 67 u64/row)
  {
    const int* adjb = adj + ((size_t)(b*GN + i0))*GN + jw;
    #pragma unroll 2
    for (int r = 0; r < 64; ++r){
      const int* src = adjb + (size_t)r*GN;
      int v[8];
      #pragma unroll
      for (int c = 0; c < 8; ++c)
        v[c] = __builtin_nontemporal_load(src + (c<<6) + lane);   // 256B/instr coalesced
      #pragma unroll
      for (int c = 0; c < 8; ++c){
        const unsigned long long mm = __ballot(v[c] > 0);
        if (lane == 0) bits64[r*67 + (wave<<3) + c] = mm;
      }
    }
  }
  __syncthreads();

  float Ti[4], Ri[4];
  #pragma unroll
  for (int g=0; g<4; ++g){
    const float siv = si_g[(size_t)b*GN + i0 + (g<<4) + m];
    Ti[g] = __expf(-siv);
    Ri[g] = __expf(-0.8f*siv);
  }
  const unsigned short* lanebase = whB + ((size_t)b<<19) + (m<<5) + q8;

  floatx4 acc[4][8];
  floatx4 lf[4];
  #pragma unroll
  for (int g=0;g<4;++g){
    #pragma unroll
    for (int c=0;c<8;++c) acc[g][c] = (floatx4){0.f,0.f,0.f,0.f};
    lf[g] = (floatx4){0.f,0.f,0.f,0.f};
  }
  const short8 ones8 = {0x3F80,0x3F80,0x3F80,0x3F80,0x3F80,0x3F80,0x3F80,0x3F80};

#define MKAF(dst_, sh_, Ti_, Ri_) do { \
    unsigned int aw[4]; \
    _Pragma("unroll") \
    for (int p=0;p<4;++p){ \
      unsigned int e0 = Eu[p] << 16, e1 = Eu[p] & 0xFFFF0000u; \
      unsigned int f0 = Fu[p] << 16, f1 = Fu[p] & 0xFFFF0000u; \
      float E0 = __uint_as_float(e0), E1 = __uint_as_float(e1); \
      float t0 = (Ri_)*__uint_as_float(f0), t1 = (Ri_)*__uint_as_float(f1); \
      float p0 = (E0 > (Ti_)) ? E0 : t0; \
      float p1 = (E1 > (Ti_)) ? E1 : t1; \
      unsigned int k0 = (unsigned int)(((int)((sh_) << (31-(2*p))))   >> 31); \
      unsigned int k1 = (unsigned int)(((int)((sh_) << (31-(2*p+1)))) >> 31); \
      unsigned int b0 = __float_as_uint(p0) & k0; \
      unsigned int b1 = __float_as_uint(p1) & k1; \
      aw[p] = ((b0 + 0x8000u) >> 16) | ((b1 + 0x8000u) & 0xFFFF0000u); \
    } \
    dst_ = *(const short8*)aw; \
  } while(0)

  #pragma unroll 2
  for (int it = 0; it < 16; ++it){
    const unsigned short* wb = lanebase + ((size_t)(jw32+it)<<12);
    short8 Bc[8];
    #pragma unroll
    for (int c=0;c<8;++c) Bc[c] = *(const short8*)(wb + (c<<9));

    const int jj = jw + (it << 5) + q8;
    const short8 Es = *(const short8*)&sEj[jj];
    const short8 Fs = *(const short8*)&sEj[4096 + jj];
    const unsigned int* Eu = (const unsigned int*)&Es;
    const unsigned int* Fu = (const unsigned int*)&Fs;

    short8 af[4];
    #pragma unroll
    for (int g=0;g<4;++g){
      const unsigned int sh = bitsW[(m + (g<<4))*134 + jw32 + it] >> q8;
      MKAF(af[g], sh, Ti[g], Ri[g]);
    }
    #pragma unroll
    for (int c=0;c<8;++c){
      #pragma unroll
      for (int g=0;g<4;++g)
        acc[g][c] = __builtin_amdgcn_mfma_f32_16x16x32_bf16(af[g], Bc[c], acc[g][c], 0, 0, 0);
    }
    #pragma unroll
    for (int g=0;g<4;++g)
      lf[g] = __builtin_amdgcn_mfma_f32_16x16x32_bf16(af[g], ones8, lf[g], 0, 0, 0);
  }
#undef MKAF

  // --- combine: fold 8 waves -> 4 regions -> final 4-way, per 16-row group ---
  #pragma unroll 1
  for (int g = 0; g < 4; ++g){
    __syncthreads();
    if (wave >= 4){
      #pragma unroll
      for (int c=0;c<8;++c){
        #pragma unroll
        for (int r=0;r<4;++r)
          smemc[((wave-4)*16 + quad*4 + r)*129 + c*16 + m] = acc[g][c][r];
      }
      if (m == 0){
        #pragma unroll
        for (int r=0;r<4;++r) smemc[8256 + (wave-4)*16 + quad*4 + r] = lf[g][r];
      }
    }
    __syncthreads();
    if (wave < 4){
      #pragma unroll
      for (int c=0;c<8;++c){
        #pragma unroll
        for (int r=0;r<4;++r){
          const int idx = (wave*16 + quad*4 + r)*129 + c*16 + m;
          smemc[idx] += acc[g][c][r];
        }
      }
      if (m == 0){
        #pragma unroll
        for (int r=0;r<4;++r) smemc[8256 + wave*16 + quad*4 + r] += lf[g][r];
      }
    }
    __syncthreads();

    #pragma unroll
    for (int k=0;k<4;++k){
      const int idx = tid + (k<<9);               // 0..2047
      const int row = idx >> 7, col = idx & 127;
      const float s = smemc[row*129+col] + smemc[(16+row)*129+col]
                    + smemc[(32+row)*129+col] + smemc[(48+row)*129+col];
      const float l = smemc[8256+row] + smemc[8256+16+row]
                    + smemc[8256+32+row] + smemc[8256+48+row];
      float v = s / l;
      v = v > 0.f ? v : expm1f(v);               // ELU (alpha=1)
      out[((size_t)(b*GN + i0 + (g<<4) + row))*GF + col] = v;
    }
  }
}

extern "C" void kernel_launch(void* const* d_in, const int* in_sizes, int n_in,
                              void* d_out, int out_size, void* d_ws, size_t ws_size,
                              hipStream_t stream)
{
  (void)in_sizes; (void)n_in; (void)out_size; (void)ws_size;
  const float* h   = (const float*)d_in[0];
  const int*   adj = (const int*)d_in[1];
  const float* W   = (const float*)d_in[2];
  const float* a   = (const float*)d_in[3];
  float* out = (float*)d_out;

  char* ws = (char*)d_ws;
  unsigned short* whB   = (unsigned short*)ws;                    // 4 MB fragment-major
  float*          si    = (float*)(ws + (size_t)4*1024*1024);     // 64 KB
  unsigned short* EFh   = (unsigned short*)(ws + (size_t)4*1024*1024 + 64*1024);   // 64 KB

  gat_prep<<<GB*GN/16, 256, 0, stream>>>(h, W, a, whB, si, EFh);
  gat_main<<<GB*GN/64, 512, 0, stream>>>(adj, whB, si, EFh, out);
}

// Round 14
// 401.287 us; speedup vs baseline: 1.0628x; 1.0628x over previous
//
#include <hip/hip_runtime.h>

#define GN 4096
#define GF 128
#define GB 4

typedef __attribute__((ext_vector_type(8))) short short8;
typedef __attribute__((ext_vector_type(4))) float floatx4;

static __device__ __forceinline__ unsigned short f2bf(float x){
  unsigned int u = __float_as_uint(x);
  u += 0x7FFFu + ((u >> 16) & 1u);            // RNE
  return (unsigned short)(u >> 16);
}

// ---------- Kernel 1: Wh = h@W (f32), si, bf16 E/F tables, bf16 Wh fragment-major ----------
// whB layout: [b][jblk=j>>5][o][j&31] so a wave's B-fragment load is 1KB contiguous.
__global__ __launch_bounds__(256)
void gat_prep(const float* __restrict__ h, const float* __restrict__ W,
              const float* __restrict__ a, unsigned short* __restrict__ whB,
              float* __restrict__ si_g, unsigned short* __restrict__ EFh)
{
  __shared__ float hl[16*GF];                  // 8 KB
  __shared__ float red[2][2][16];
  const int tid = threadIdx.x;
  const int b   = blockIdx.x >> 8;
  const int r0  = (blockIdx.x & 255) << 4;
  const int o = tid & 127, g = tid >> 7;

  const float4* hb4 = (const float4*)(h + ((size_t)(b*GN + r0))*GF);
  ((float4*)hl)[tid]       = hb4[tid];
  ((float4*)hl)[tid + 256] = hb4[tid + 256];
  __syncthreads();

  float acc[8];
  #pragma unroll
  for (int r=0;r<8;++r) acc[r] = 0.f;
  const float* Wp = W + o;
  for (int f4=0; f4<32; ++f4){
    const float w0 = Wp[(f4*4+0)*GF];
    const float w1 = Wp[(f4*4+1)*GF];
    const float w2 = Wp[(f4*4+2)*GF];
    const float w3 = Wp[(f4*4+3)*GF];
    #pragma unroll
    for (int r=0;r<8;++r){
      const float4 h4 = *(const float4*)&hl[((g<<3)+r)*GF + (f4<<2)];
      acc[r] = fmaf(h4.x, w0, acc[r]);
      acc[r] = fmaf(h4.y, w1, acc[r]);
      acc[r] = fmaf(h4.z, w2, acc[r]);
      acc[r] = fmaf(h4.w, w3, acc[r]);
    }
  }

  const float ai = a[o], aj = a[GF + o];
  const int lane = tid & 63, wh = (tid >> 6) & 1;
  #pragma unroll
  for (int r=0;r<8;++r){
    float vi = acc[r]*ai, vj = acc[r]*aj;
    #pragma unroll
    for (int off=32; off; off>>=1){ vi += __shfl_down(vi, off); vj += __shfl_down(vj, off); }
    if (lane == 0){ red[0][wh][(g<<3)+r] = vi; red[1][wh][(g<<3)+r] = vj; }
  }

  // fragment-major bf16 store
  unsigned short us[8] __attribute__((aligned(16)));
  #pragma unroll
  for (int r=0;r<8;++r) us[r] = f2bf(acc[r]);
  {
    const int j0 = r0 + (g<<3);
    unsigned short* dst = whB + (((size_t)(b*128 + (j0>>5))*128 + o)<<5) + (j0&31);
    *(uint4*)dst = *(const uint4*)us;
  }

  __syncthreads();
  if (tid < 16){
    si_g[b*GN + r0 + tid] = red[0][0][tid] + red[0][1][tid];
  } else if (tid < 32){
    const int r = tid - 16;
    const float vsj = red[1][0][r] + red[1][1][r];
    EFh[(size_t)b*8192 + r0 + r]        = f2bf(__expf(vsj));
    EFh[(size_t)b*8192 + 4096 + r0 + r] = f2bf(__expf(0.2f*vsj));
  }
}

// ---------- Kernel 2: fused adj-pack + attention + PV; 32 i-rows/block ----------
// r12 structure verbatim; only change: launch_bounds min-waves 2 -> 3
// (VGPR cap 170 > ~130 needed; LDS 33.5KB; target 3 blocks/CU = 12 waves/CU).
__global__ __launch_bounds__(256, 3)
void gat_main(const int* __restrict__ adj, const unsigned short* __restrict__ whB,
              const float* __restrict__ si_g, const unsigned short* __restrict__ EFh,
              float* __restrict__ out)
{
  __shared__ __align__(16) char smem[16384 + 32*134*4];             // 33.5 KB union
  unsigned short* sEj = (unsigned short*)smem;                      // [0,4096):E [4096,8192):F
  unsigned int*   bitsW  = (unsigned int*)(smem + 16384);           // [32][134]
  unsigned long long* bits64 = (unsigned long long*)(smem + 16384); // [32][67]
  float* smemc = (float*)smem;                                      // combine (after K-loop)

  const int tid  = threadIdx.x;
  const int wave = tid >> 6, lane = tid & 63;
  const int b  = (blockIdx.x >> 1) & 3;                             // XCD-pair per batch
  const int i0 = ((((blockIdx.x >> 3) << 1) | (blockIdx.x & 1))) << 5;
  const int m = lane & 15, quad = lane >> 4, q8 = quad << 3;

  const int jw = wave << 10, jw32 = wave << 5;

  // --- EF staging (16KB) ---
  {
    const uint4* Eg = (const uint4*)(EFh + (size_t)b*8192);
    uint4* sE4 = (uint4*)sEj;
    #pragma unroll
    for (int k=0;k<4;++k) sE4[tid + (k<<8)] = Eg[tid + (k<<8)];
  }

  // --- Phase 1: pack this block's adj tile (32 rows x this wave's 1024 j) ---
  // wave w emits 16 u64 words per row at word offset w*16  (stride 67 u64/row)
  {
    const int* adjb = adj + ((size_t)(b*GN + i0))*GN + jw;
    #pragma unroll 2
    for (int r = 0; r < 32; ++r){
      const int* src = adjb + (size_t)r*GN;
      int v[16];
      #pragma unroll
      for (int c = 0; c < 16; ++c)
        v[c] = __builtin_nontemporal_load(src + (c<<6) + lane);   // 256B/instr coalesced
      #pragma unroll
      for (int c = 0; c < 16; ++c){
        const unsigned long long mm = __ballot(v[c] > 0);
        if (lane == 0) bits64[r*67 + (wave<<4) + c] = mm;         // <<4 (16 words/wave)
      }
    }
  }
  __syncthreads();

  const float si0 = si_g[(size_t)b*GN + i0 + m];
  const float si1 = si_g[(size_t)b*GN + i0 + 16 + m];
  const float Ti0 = __expf(-si0),      Ti1 = __expf(-si1);
  const float Ri0 = __expf(-0.8f*si0), Ri1 = __expf(-0.8f*si1);
  const unsigned short* lanebase = whB + ((size_t)b<<19) + (m<<5) + q8;

  floatx4 acc0[8], acc1[8];
  #pragma unroll
  for (int c=0;c<8;++c){ acc0[c] = (floatx4){0.f,0.f,0.f,0.f}; acc1[c] = (floatx4){0.f,0.f,0.f,0.f}; }
  floatx4 lf0 = (floatx4){0.f,0.f,0.f,0.f}, lf1 = (floatx4){0.f,0.f,0.f,0.f};
  const short8 ones8 = {0x3F80,0x3F80,0x3F80,0x3F80,0x3F80,0x3F80,0x3F80,0x3F80};

#define MKAF(dst_, sh_, Ti_, Ri_) do { \
    unsigned int aw[4]; \
    _Pragma("unroll") \
    for (int p=0;p<4;++p){ \
      unsigned int e0 = Eu[p] << 16, e1 = Eu[p] & 0xFFFF0000u; \
      unsigned int f0 = Fu[p] << 16, f1 = Fu[p] & 0xFFFF0000u; \
      float E0 = __uint_as_float(e0), E1 = __uint_as_float(e1); \
      float t0 = (Ri_)*__uint_as_float(f0), t1 = (Ri_)*__uint_as_float(f1); \
      float p0 = (E0 > (Ti_)) ? E0 : t0; \
      float p1 = (E1 > (Ti_)) ? E1 : t1; \
      unsigned int k0 = (unsigned int)(((int)((sh_) << (31-(2*p))))   >> 31); \
      unsigned int k1 = (unsigned int)(((int)((sh_) << (31-(2*p+1)))) >> 31); \
      unsigned int b0 = __float_as_uint(p0) & k0; \
      unsigned int b1 = __float_as_uint(p1) & k1; \
      aw[p] = ((b0 + 0x8000u) >> 16) | ((b1 + 0x8000u) & 0xFFFF0000u); \
    } \
    dst_ = *(const short8*)aw; \
  } while(0)

  #pragma unroll 2
  for (int it = 0; it < 32; ++it){
    const unsigned short* wb = lanebase + ((size_t)(jw32+it)<<12);
    short8 Bc[8];
    #pragma unroll
    for (int c=0;c<8;++c) Bc[c] = *(const short8*)(wb + (c<<9));

    const unsigned int sh0 = bitsW[m*134 + jw32 + it] >> q8;
    const unsigned int sh1 = bitsW[(m+16)*134 + jw32 + it] >> q8;
    const int jj = jw + (it << 5) + q8;
    const short8 Es = *(const short8*)&sEj[jj];
    const short8 Fs = *(const short8*)&sEj[4096 + jj];
    const unsigned int* Eu = (const unsigned int*)&Es;
    const unsigned int* Fu = (const unsigned int*)&Fs;
    short8 af0, af1;
    MKAF(af0, sh0, Ti0, Ri0);
    MKAF(af1, sh1, Ti1, Ri1);
    #pragma unroll
    for (int c=0;c<8;++c){
      acc0[c] = __builtin_amdgcn_mfma_f32_16x16x32_bf16(af0, Bc[c], acc0[c], 0, 0, 0);
      acc1[c] = __builtin_amdgcn_mfma_f32_16x16x32_bf16(af1, Bc[c], acc1[c], 0, 0, 0);
    }
    lf0 = __builtin_amdgcn_mfma_f32_16x16x32_bf16(af0, ones8, lf0, 0, 0, 0);
    lf1 = __builtin_amdgcn_mfma_f32_16x16x32_bf16(af1, ones8, lf1, 0, 0, 0);
  }
#undef MKAF

  // cross-wave combine, two passes (rowgroup 0 then 1), reusing unioned LDS
  #pragma unroll 1
  for (int g = 0; g < 2; ++g){
    __syncthreads();
    #pragma unroll
    for (int c=0;c<8;++c){
      #pragma unroll
      for (int r=0;r<4;++r){
        const float v = g ? acc1[c][r] : acc0[c][r];
        smemc[(wave*16 + quad*4 + r)*129 + c*16 + m] = v;
      }
    }
    if (m == 0){
      #pragma unroll
      for (int r=0;r<4;++r) smemc[8256 + wave*16 + quad*4 + r] = g ? lf1[r] : lf0[r];
    }
    __syncthreads();

    #pragma unroll
    for (int k=0;k<8;++k){
      const int idx = tid + (k<<8);
      const int row = idx >> 7, col = idx & 127;
      const float s = smemc[row*129+col] + smemc[(16+row)*129+col]
                    + smemc[(32+row)*129+col] + smemc[(48+row)*129+col];
      const float l = smemc[8256+row] + smemc[8256+16+row]
                    + smemc[8256+32+row] + smemc[8256+48+row];
      float v = s / l;
      v = v > 0.f ? v : expm1f(v);             // ELU (alpha=1)
      out[((size_t)(b*GN + i0 + (g<<4) + row))*GF + col] = v;
    }
  }
}

extern "C" void kernel_launch(void* const* d_in, const int* in_sizes, int n_in,
                              void* d_out, int out_size, void* d_ws, size_t ws_size,
                              hipStream_t stream)
{
  (void)in_sizes; (void)n_in; (void)out_size; (void)ws_size;
  const float* h   = (const float*)d_in[0];
  const int*   adj = (const int*)d_in[1];
  const float* W   = (const float*)d_in[2];
  const float* a   = (const float*)d_in[3];
  float* out = (float*)d_out;

  char* ws = (char*)d_ws;
  unsigned short* whB   = (unsigned short*)ws;                    // 4 MB fragment-major
  float*          si    = (float*)(ws + (size_t)4*1024*1024);     // 64 KB
  unsigned short* EFh   = (unsigned short*)(ws + (size_t)4*1024*1024 + 64*1024);   // 64 KB

  gat_prep<<<GB*GN/16, 256, 0, stream>>>(h, W, a, whB, si, EFh);
  gat_main<<<GB*GN/32, 256, 0, stream>>>(adj, whB, si, EFh, out);
}